// Round 2
// baseline (756.108 us; speedup 1.0000x reference)
//
#include <hip/hip_runtime.h>
#include <cstdint>
#include <cstddef>

using u16 = unsigned short;
typedef __bf16 bf16x8 __attribute__((ext_vector_type(8)));
typedef float f32x4 __attribute__((ext_vector_type(4)));

#define T_TOK 4096
#define HDIM 1024
#define EXP 8
#define IDIM 4096
#define NROWS 8192      // T_TOK * 2 (top-2 always selects 2 distinct experts)
#define PAD_ROWS 8448   // +256 so last-tile OOB row reads stay inside ws
#define BM 256          // grouped-GEMM row tile (8-phase template)
#define MAX_TILES 40    // sum ceil(n_e/256) <= 32 + 7

__device__ __forceinline__ u16 f2bf(float f) {
  union { float f; uint32_t u; } v; v.f = f;
  uint32_t u = v.u;
  u += 0x7fffu + ((u >> 16) & 1u);   // RNE
  return (u16)(u >> 16);
}

__device__ __forceinline__ void async_copy16(const u16* g, u16* s) {
  __builtin_amdgcn_global_load_lds((__attribute__((address_space(1))) void*)(void*)g,
                                   (__attribute__((address_space(3))) void*)s, 16, 0, 0);
}

// ---------------- gating: fp32 logits, softmax/top-2/renorm -----------------
__global__ __launch_bounds__(256) void gate_kernel(const float* __restrict__ x,
                                                   const float* __restrict__ Wg,
                                                   int* __restrict__ sel_e,
                                                   float* __restrict__ sel_w) {
  int lane = threadIdx.x & 63;
  int wave = threadIdx.x >> 6;
  int t = blockIdx.x * 4 + wave;
  const float* xr = x + (size_t)t * HDIM;
  float p[8];
#pragma unroll
  for (int e = 0; e < 8; ++e) p[e] = 0.f;
#pragma unroll
  for (int i = 0; i < 16; ++i) {
    int h = i * 64 + lane;
    float xv = xr[h];
    const float4* w4 = (const float4*)(Wg + h * 8);
    float4 a = w4[0], b = w4[1];
    p[0] += xv * a.x; p[1] += xv * a.y; p[2] += xv * a.z; p[3] += xv * a.w;
    p[4] += xv * b.x; p[5] += xv * b.y; p[6] += xv * b.z; p[7] += xv * b.w;
  }
#pragma unroll
  for (int e = 0; e < 8; ++e) {
#pragma unroll
    for (int off = 32; off > 0; off >>= 1) p[e] += __shfl_xor(p[e], off);
  }
  if (lane == 0) {
    int e0 = 0; float m0 = p[0];
#pragma unroll
    for (int e = 1; e < 8; ++e) { if (p[e] > m0) { m0 = p[e]; e0 = e; } }
    int e1 = -1; float m1 = -3.4e38f;
#pragma unroll
    for (int e = 0; e < 8; ++e) { if (e != e0 && p[e] > m1) { m1 = p[e]; e1 = e; } }
    float r = expf(m1 - m0);
    float w0 = 1.f / (1.f + r);
    float w1 = r / (1.f + r);
    sel_e[2 * t] = e0; sel_e[2 * t + 1] = e1;
    sel_w[2 * t] = w0; sel_w[2 * t + 1] = w1;
  }
}

// ---------------- routing: counting sort + 256-row tile descriptors ---------
__global__ void route_kernel(const int* __restrict__ sel_e, const float* __restrict__ sel_w,
                             int* __restrict__ row_token, float* __restrict__ row_weight,
                             int* __restrict__ tile_e, int* __restrict__ tile_m0,
                             int* __restrict__ tile_nrows, int* __restrict__ num_tiles) {
  __shared__ int cnt[EXP], off[EXP], cur[EXP];
  int tid = threadIdx.x;
  if (tid < EXP) { cnt[tid] = 0; cur[tid] = 0; }
  __syncthreads();
  for (int i = tid; i < NROWS; i += 256) atomicAdd(&cnt[sel_e[i]], 1);
  __syncthreads();
  if (tid == 0) {
    int running = 0, nt = 0;
    for (int e = 0; e < EXP; ++e) {
      off[e] = running;
      int c = cnt[e];
      int ntile = (c + BM - 1) / BM;
      for (int j = 0; j < ntile; ++j) {
        tile_e[nt] = e;
        tile_m0[nt] = running + j * BM;
        tile_nrows[nt] = min(BM, c - j * BM);
        ++nt;
      }
      running += c;
    }
    *num_tiles = nt;
  }
  __syncthreads();
  for (int i = tid; i < NROWS; i += 256) {
    int e = sel_e[i];
    int pos = off[e] + atomicAdd(&cur[e], 1);
    row_token[pos] = i >> 1;
    row_weight[pos] = sel_w[i];
  }
}

// ---------------- gather x rows -> contiguous bf16 A matrix ----------------
__global__ __launch_bounds__(256) void gather_kernel(const float* __restrict__ x,
                                                     const int* __restrict__ row_token,
                                                     u16* __restrict__ xg) {
  int r = blockIdx.x;
  int tok = row_token[r];
  const float4* xs = (const float4*)(x + (size_t)tok * HDIM);
  float4 v = xs[threadIdx.x];
  ushort4 o;
  o.x = f2bf(v.x); o.y = f2bf(v.y); o.z = f2bf(v.z); o.w = f2bf(v.w);
  *(ushort4*)(xg + (size_t)r * HDIM + threadIdx.x * 4) = o;
}

// -------- weight fp32 [E][R][C] -> bf16 [E][C][R] (B^T layout for GEMM) ----
// pad 65: stride 130 B == 2 banks mod 32 -> transpose-read phase conflict-free
__global__ __launch_bounds__(256) void transpose_convert(const float* __restrict__ src,
                                                         u16* __restrict__ dst, int R, int C) {
  int eb = blockIdx.z;
  const float* s = src + (size_t)eb * R * C;
  u16* d = dst + (size_t)eb * R * C;
  int cb = blockIdx.x * 64, rb = blockIdx.y * 64;
  __shared__ u16 tile[64][65];
  int tid = threadIdx.x;
#pragma unroll
  for (int i = 0; i < 4; ++i) {
    int idx = i * 256 + tid;
    int r = idx >> 4;
    int cq = (idx & 15) * 4;
    float4 v = *(const float4*)(s + (size_t)(rb + r) * C + cb + cq);
    tile[r][cq]     = f2bf(v.x);
    tile[r][cq + 1] = f2bf(v.y);
    tile[r][cq + 2] = f2bf(v.z);
    tile[r][cq + 3] = f2bf(v.w);
  }
  __syncthreads();
#pragma unroll
  for (int i = 0; i < 4; ++i) {
    int idx = i * 256 + tid;
    int c = idx >> 4;
    int rq = (idx & 15) * 4;
    ushort4 o;
    o.x = tile[rq][c]; o.y = tile[rq + 1][c]; o.z = tile[rq + 2][c]; o.w = tile[rq + 3][c];
    *(ushort4*)(d + (size_t)(cb + c) * R + rb + rq) = o;
  }
}

// ---------------- grouped GEMM, 256-row 8-phase schedule (T2+T3+T4+T5) -----
// A [rows][K] bf16 (expert-grouped), B [E][N][K] bf16 (pre-transposed).
// 8 waves (2M x 4N), per-wave 128 x (BNH*32) output, BK=64, LDS double-buffered
// (A: 2 halves of 128x64; B: BNH halves). XOR chunk-swizzle: 16B chunk (row,j)
// lives at slot j^(row&7); global_load_lds keeps lane-linear LDS dest, lanes
// fetch the permuted global chunk. Per K-tile group of 4 phases:
//   q0: read B-frags + A-frags(am0,1), stage A-half0(kt+1)  [other buffer]
//   q1: A-frags(am2,3),               stage A-half1(kt+1)
//   q2: A-frags(am4,5),               stage B-half0(kt+2)   [B reads done @q0]
//   q3: A-frags(am6,7), stage B-half1(kt+2), s_waitcnt vmcnt(4|2)  <- counted,
//       never 0: leaves exactly the B(kt+2) loads in flight.
// Each phase: raw s_barrier -> setprio(1) -> MFMA quadrant -> setprio(0) -> barrier.
// Tail: prefetch source k-tile clamped to KT-1 (writes land in the unread
// buffer), keeping vmcnt immediates uniform with no tail races.
template <int K, int BNH, bool SECOND>
__global__ __launch_bounds__(512, 2) void ffn_gemm8(
    const u16* __restrict__ A, const u16* __restrict__ B,
    const float* __restrict__ bias, u16* __restrict__ hdn_out,
    float* __restrict__ out, const int* __restrict__ row_token,
    const float* __restrict__ row_weight, const int* __restrict__ tile_e,
    const int* __restrict__ tile_m0, const int* __restrict__ tile_nrows,
    const int* __restrict__ num_tiles, int N) {
  constexpr int AN = BNH * 2;     // 16-wide col fragments per wave
  constexpr int KT = K / 64;
  int ty = blockIdx.y;
  if (ty >= *num_tiles) return;
  int e = tile_e[ty];
  int row0 = tile_m0[ty];
  int nrows = tile_nrows[ty];
  int n0 = blockIdx.x * (BNH * 128);

  __shared__ u16 sA[2][2 * 128 * 64];
  __shared__ u16 sB[2][BNH * 128 * 64];

  int tid = threadIdx.x;
  int lane = tid & 63;
  int wave = tid >> 6;             // 0..7
  int wm = wave >> 2, wn = wave & 3;
  int l15 = lane & 15, quad = lane >> 4;
  int r7 = l15 & 7;

  const u16* Ab = A + (size_t)row0 * K;
  const u16* Bb = B + (size_t)e * (size_t)N * K + (size_t)n0 * K;

  // half-tile staging: 128 rows x 64 bf16 = 16 KB = 512 thr x 2 x 16 B
  int c0 = tid, c1 = tid + 512;
  int r0 = c0 >> 3, j0 = ((c0 & 7) ^ (r0 & 7)) * 8;
  int r1 = c1 >> 3, j1 = ((c1 & 7) ^ (r1 & 7)) * 8;

  auto stageA = [&](int db, int sk, int ha) {
    async_copy16(Ab + (size_t)(ha * 128 + r0) * K + sk * 64 + j0, &sA[db][ha * 8192 + c0 * 8]);
    async_copy16(Ab + (size_t)(ha * 128 + r1) * K + sk * 64 + j1, &sA[db][ha * 8192 + c1 * 8]);
  };
  auto stageB = [&](int db, int sk, int hb) {
    async_copy16(Bb + (size_t)(hb * 128 + r0) * K + sk * 64 + j0, &sB[db][hb * 8192 + c0 * 8]);
    async_copy16(Bb + (size_t)(hb * 128 + r1) * K + sk * 64 + j1, &sB[db][hb * 8192 + c1 * 8]);
  };

  int jx[2];
#pragma unroll
  for (int ks = 0; ks < 2; ++ks) jx[ks] = ((ks * 4 + quad) ^ r7) * 8;

  f32x4 acc[8][AN];
#pragma unroll
  for (int am = 0; am < 8; ++am)
#pragma unroll
    for (int an = 0; an < AN; ++an) acc[am][an] = (f32x4){0.f, 0.f, 0.f, 0.f};

  // prologue: K-tile 0 fully + B of K-tile 1 (A of 1 staged in group 0)
  stageA(0, 0, 0); stageA(0, 0, 1);
  stageB(0, 0, 0);
  if constexpr (BNH == 2) stageB(0, 0, 1);
  stageB(1, 1, 0);
  if constexpr (BNH == 2) stageB(1, 1, 1);
  if constexpr (BNH == 2) { asm volatile("s_waitcnt vmcnt(4)" ::: "memory"); }
  else                    { asm volatile("s_waitcnt vmcnt(2)" ::: "memory"); }
  __builtin_amdgcn_s_barrier();

#define PHASE(Q, STAGE_STMT, WAIT_STMT)                                               \
  {                                                                                   \
    bf16x8 af[2][2];                                                                  \
    _Pragma("unroll")                                                                 \
    for (int ks = 0; ks < 2; ++ks)                                                    \
      _Pragma("unroll")                                                               \
      for (int i = 0; i < 2; ++i)                                                     \
        af[i][ks] = *(const bf16x8*)(sAc + (wm * 128 + (2 * (Q) + i) * 16 + l15) * 64 \
                                     + jx[ks]);                                       \
    STAGE_STMT;                                                                       \
    WAIT_STMT;                                                                        \
    __builtin_amdgcn_s_barrier();                                                     \
    __builtin_amdgcn_s_setprio(1);                                                    \
    _Pragma("unroll")                                                                 \
    for (int i = 0; i < 2; ++i)                                                       \
      _Pragma("unroll")                                                               \
      for (int an = 0; an < AN; ++an)                                                 \
        _Pragma("unroll")                                                             \
        for (int ks = 0; ks < 2; ++ks)                                                \
          acc[2 * (Q) + i][an] = __builtin_amdgcn_mfma_f32_16x16x32_bf16(             \
              af[i][ks], bfr[an][ks], acc[2 * (Q) + i][an], 0, 0, 0);                 \
    __builtin_amdgcn_s_setprio(0);                                                    \
    __builtin_amdgcn_s_barrier();                                                     \
  }

  for (int kt = 0; kt < KT; ++kt) {
    int cb = kt & 1, nb = cb ^ 1;
    int ka = kt + 1 < KT ? kt + 1 : KT - 1;
    int kb = kt + 2 < KT ? kt + 2 : KT - 1;
    const u16* sAc = sA[cb];
    const u16* sBc = sB[cb];
    bf16x8 bfr[AN][2];
#pragma unroll
    for (int ks = 0; ks < 2; ++ks)
#pragma unroll
      for (int an = 0; an < AN; ++an)
        bfr[an][ks] = *(const bf16x8*)(sBc + ((wn * AN + an) * 16 + l15) * 64 + jx[ks]);
    PHASE(0, stageA(nb, ka, 0), )
    PHASE(1, stageA(nb, ka, 1), )
    PHASE(2, stageB(cb, kb, 0), )
    if constexpr (BNH == 2) {
      PHASE(3, stageB(cb, kb, 1), asm volatile("s_waitcnt vmcnt(4)" ::: "memory"))
    } else {
      PHASE(3, , asm volatile("s_waitcnt vmcnt(2)" ::: "memory"))
    }
  }
#undef PHASE

  if constexpr (!SECOND) {
#pragma unroll
    for (int an = 0; an < AN; ++an) {
      int col = n0 + (wn * AN + an) * 16 + l15;
      float bv = bias[e * N + col];
#pragma unroll
      for (int am = 0; am < 8; ++am) {
#pragma unroll
        for (int r = 0; r < 4; ++r) {
          int lr = wm * 128 + am * 16 + quad * 4 + r;  // C/D: col=lane&15, row=quad*4+reg
          if (lr < nrows) {
            float vv = acc[am][an][r] + bv;
            vv = vv / (1.f + __expf(-vv));             // silu
            hdn_out[(size_t)(row0 + lr) * N + col] = f2bf(vv);
          }
        }
      }
    }
  } else {
    float bv[AN];
#pragma unroll
    for (int an = 0; an < AN; ++an) bv[an] = bias[e * N + n0 + (wn * AN + an) * 16 + l15];
#pragma unroll
    for (int am = 0; am < 8; ++am) {
#pragma unroll
      for (int r = 0; r < 4; ++r) {
        int lr = wm * 128 + am * 16 + quad * 4 + r;
        if (lr < nrows) {
          int grow = row0 + lr;
          int tok = row_token[grow];
          float w = row_weight[grow];
          float* orow = out + (size_t)tok * N;
#pragma unroll
          for (int an = 0; an < AN; ++an) {
            int col = n0 + (wn * AN + an) * 16 + l15;
            atomicAdd(orow + col, (acc[am][an][r] + bv[an]) * w);
          }
        }
      }
    }
  }
}

extern "C" void kernel_launch(void* const* d_in, const int* in_sizes, int n_in,
                              void* d_out, int out_size, void* d_ws, size_t ws_size,
                              hipStream_t stream) {
  const float* x  = (const float*)d_in[0];
  const float* Wg = (const float*)d_in[1];
  const float* W1 = (const float*)d_in[2];
  const float* b1 = (const float*)d_in[3];
  const float* W2 = (const float*)d_in[4];
  const float* b2 = (const float*)d_in[5];
  float* out = (float*)d_out;

  char* ws = (char*)d_ws;
  size_t off = 0;
  auto alloc = [&](size_t bytes) {
    void* p = ws + off;
    off += (bytes + 255) & ~(size_t)255;
    return p;
  };
  u16* W1T = (u16*)alloc((size_t)EXP * IDIM * HDIM * 2);   // 67 MB  [E][I][H]
  u16* W2T = (u16*)alloc((size_t)EXP * IDIM * HDIM * 2);   // 67 MB  [E][H][I]
  u16* xg  = (u16*)alloc((size_t)PAD_ROWS * HDIM * 2);     // 17 MB
  u16* hdn = (u16*)alloc((size_t)PAD_ROWS * IDIM * 2);     // 69 MB
  int*   sel_e      = (int*)alloc(NROWS * 4);
  float* sel_w      = (float*)alloc(NROWS * 4);
  int*   row_token  = (int*)alloc(NROWS * 4);
  float* row_weight = (float*)alloc(NROWS * 4);
  int* tile_e     = (int*)alloc(MAX_TILES * 4);
  int* tile_m0    = (int*)alloc(MAX_TILES * 4);
  int* tile_nrows = (int*)alloc(MAX_TILES * 4);
  int* num_tiles  = (int*)alloc(4);

  hipMemsetAsync(d_out, 0, (size_t)out_size * sizeof(float), stream);
  transpose_convert<<<dim3(IDIM / 64, HDIM / 64, EXP), 256, 0, stream>>>(W1, W1T, HDIM, IDIM);
  transpose_convert<<<dim3(HDIM / 64, IDIM / 64, EXP), 256, 0, stream>>>(W2, W2T, IDIM, HDIM);
  gate_kernel<<<T_TOK / 4, 256, 0, stream>>>(x, Wg, sel_e, sel_w);
  route_kernel<<<1, 256, 0, stream>>>(sel_e, sel_w, row_token, row_weight,
                                      tile_e, tile_m0, tile_nrows, num_tiles);
  gather_kernel<<<NROWS, 256, 0, stream>>>(x, row_token, xg);
  ffn_gemm8<HDIM, 2, false><<<dim3(IDIM / 256, MAX_TILES), 512, 0, stream>>>(
      xg, W1T, b1, hdn, nullptr, nullptr, nullptr,
      tile_e, tile_m0, tile_nrows, num_tiles, IDIM);
  ffn_gemm8<IDIM, 1, true><<<dim3(HDIM / 128, MAX_TILES), 512, 0, stream>>>(
      hdn, W2T, b2, nullptr, out, row_token, row_weight,
      tile_e, tile_m0, tile_nrows, num_tiles, HDIM);
}

// Round 3
// 674.394 us; speedup vs baseline: 1.1212x; 1.1212x over previous
//
#include <hip/hip_runtime.h>
#include <cstdint>
#include <cstddef>

using u16 = unsigned short;
typedef __bf16 bf16x8 __attribute__((ext_vector_type(8)));
typedef float f32x4 __attribute__((ext_vector_type(4)));

#define T_TOK 4096
#define HDIM 1024
#define EXP 8
#define IDIM 4096
#define NROWS 8192      // T_TOK * 2 (top-2 always selects 2 distinct experts)
#define PAD_ROWS 8448   // +256 so last-tile OOB row reads stay inside ws
#define BM 256          // grouped-GEMM row tile
#define MAX_TILES 40    // sum ceil(n_e/256) <= 32 + 7

__device__ __forceinline__ u16 f2bf(float f) {
  union { float f; uint32_t u; } v; v.f = f;
  uint32_t u = v.u;
  u += 0x7fffu + ((u >> 16) & 1u);   // RNE
  return (u16)(u >> 16);
}

__device__ __forceinline__ void async_copy16(const u16* g, u16* s) {
  __builtin_amdgcn_global_load_lds((__attribute__((address_space(1))) void*)(void*)g,
                                   (__attribute__((address_space(3))) void*)s, 16, 0, 0);
}

// ---------------- gating: fp32 logits, softmax/top-2/renorm -----------------
__global__ __launch_bounds__(256) void gate_kernel(const float* __restrict__ x,
                                                   const float* __restrict__ Wg,
                                                   int* __restrict__ sel_e,
                                                   float* __restrict__ sel_w) {
  int lane = threadIdx.x & 63;
  int wave = threadIdx.x >> 6;
  int t = blockIdx.x * 4 + wave;
  const float* xr = x + (size_t)t * HDIM;
  float p[8];
#pragma unroll
  for (int e = 0; e < 8; ++e) p[e] = 0.f;
#pragma unroll
  for (int i = 0; i < 16; ++i) {
    int h = i * 64 + lane;
    float xv = xr[h];
    const float4* w4 = (const float4*)(Wg + h * 8);
    float4 a = w4[0], b = w4[1];
    p[0] += xv * a.x; p[1] += xv * a.y; p[2] += xv * a.z; p[3] += xv * a.w;
    p[4] += xv * b.x; p[5] += xv * b.y; p[6] += xv * b.z; p[7] += xv * b.w;
  }
#pragma unroll
  for (int e = 0; e < 8; ++e) {
#pragma unroll
    for (int off = 32; off > 0; off >>= 1) p[e] += __shfl_xor(p[e], off);
  }
  if (lane == 0) {
    int e0 = 0; float m0 = p[0];
#pragma unroll
    for (int e = 1; e < 8; ++e) { if (p[e] > m0) { m0 = p[e]; e0 = e; } }
    int e1 = -1; float m1 = -3.4e38f;
#pragma unroll
    for (int e = 0; e < 8; ++e) { if (e != e0 && p[e] > m1) { m1 = p[e]; e1 = e; } }
    float r = expf(m1 - m0);
    float w0 = 1.f / (1.f + r);
    float w1 = r / (1.f + r);
    sel_e[2 * t] = e0; sel_e[2 * t + 1] = e1;
    sel_w[2 * t] = w0; sel_w[2 * t + 1] = w1;
  }
}

// ---------------- routing: counting sort + 256-row tile descriptors ---------
// Also zeroes the two persistent-GEMM work counters each launch (graph replay).
__global__ void route_kernel(const int* __restrict__ sel_e, const float* __restrict__ sel_w,
                             int* __restrict__ row_token, float* __restrict__ row_weight,
                             int* __restrict__ tile_e, int* __restrict__ tile_m0,
                             int* __restrict__ tile_nrows, int* __restrict__ num_tiles,
                             int* __restrict__ work_ctr) {
  __shared__ int cnt[EXP], off[EXP], cur[EXP];
  int tid = threadIdx.x;
  if (tid < EXP) { cnt[tid] = 0; cur[tid] = 0; }
  if (tid < 2) work_ctr[tid] = 0;
  __syncthreads();
  for (int i = tid; i < NROWS; i += 256) atomicAdd(&cnt[sel_e[i]], 1);
  __syncthreads();
  if (tid == 0) {
    int running = 0, nt = 0;
    for (int e = 0; e < EXP; ++e) {
      off[e] = running;
      int c = cnt[e];
      int ntile = (c + BM - 1) / BM;
      for (int j = 0; j < ntile; ++j) {
        tile_e[nt] = e;
        tile_m0[nt] = running + j * BM;
        tile_nrows[nt] = min(BM, c - j * BM);
        ++nt;
      }
      running += c;
    }
    *num_tiles = nt;
  }
  __syncthreads();
  for (int i = tid; i < NROWS; i += 256) {
    int e = sel_e[i];
    int pos = off[e] + atomicAdd(&cur[e], 1);
    row_token[pos] = i >> 1;
    row_weight[pos] = sel_w[i];
  }
}

// ---------------- gather x rows -> contiguous bf16 A matrix ----------------
__global__ __launch_bounds__(256) void gather_kernel(const float* __restrict__ x,
                                                     const int* __restrict__ row_token,
                                                     u16* __restrict__ xg) {
  int r = blockIdx.x;
  int tok = row_token[r];
  const float4* xs = (const float4*)(x + (size_t)tok * HDIM);
  float4 v = xs[threadIdx.x];
  ushort4 o;
  o.x = f2bf(v.x); o.y = f2bf(v.y); o.z = f2bf(v.z); o.w = f2bf(v.w);
  *(ushort4*)(xg + (size_t)r * HDIM + threadIdx.x * 4) = o;
}

// -------- weight fp32 [E][R][C] -> bf16 [E][C][R] (B^T layout for GEMM) ----
__global__ __launch_bounds__(256) void transpose_convert(const float* __restrict__ src,
                                                         u16* __restrict__ dst, int R, int C) {
  int eb = blockIdx.z;
  const float* s = src + (size_t)eb * R * C;
  u16* d = dst + (size_t)eb * R * C;
  int cb = blockIdx.x * 64, rb = blockIdx.y * 64;
  __shared__ u16 tile[64][65];
  int tid = threadIdx.x;
#pragma unroll
  for (int i = 0; i < 4; ++i) {
    int idx = i * 256 + tid;
    int r = idx >> 4;
    int cq = (idx & 15) * 4;
    float4 v = *(const float4*)(s + (size_t)(rb + r) * C + cb + cq);
    tile[r][cq]     = f2bf(v.x);
    tile[r][cq + 1] = f2bf(v.y);
    tile[r][cq + 2] = f2bf(v.z);
    tile[r][cq + 3] = f2bf(v.w);
  }
  __syncthreads();
#pragma unroll
  for (int i = 0; i < 4; ++i) {
    int idx = i * 256 + tid;
    int c = idx >> 4;
    int rq = (idx & 15) * 4;
    ushort4 o;
    o.x = tile[rq][c]; o.y = tile[rq + 1][c]; o.z = tile[rq + 2][c]; o.w = tile[rq + 3][c];
    *(ushort4*)(d + (size_t)(cb + c) * R + rb + rq) = o;
  }
}

// ---------------- persistent grouped GEMM, 2-phase/K-tile, 16 MFMA/phase ---
// A [rows][K] bf16 (expert-grouped), B [E][N][K] bf16 (pre-transposed).
// BM=256, BN=128, 8 waves (2M x 4N), per-wave 128x32, acc[8][2].
// Work item = (tile, nb[, ksplit]); grabbed via global atomic, broadcast in LDS.
// LDS dbuf: sA 2x(256x64)=64KB, sB 2x(128x64)=32KB. XOR chunk swizzle: 16B
// chunk (row,j) lives at slot j^(row&7); staged lane-linear via pre-permuted
// global source (global_load_lds needs linear LDS dest).
// Per K-tile kt (cb=kt&1, pb=cb^1):
//   top: bfr[2][2] <- sB[cb]                       (4 ds_read_b128)
//   PH0: af rows0-3 (8 ds_read); stage A(kt+1) both halves -> sA[pb];
//        barrier; prio1; 16 MFMA; prio0; barrier
//   PH1: af rows4-7 (8 ds_read); stage B(kt+2) -> sB[cb] (safe: bfr consumed
//        before PH0's closing barrier); s_waitcnt vmcnt(2)  <- counted, never
//        0: leaves exactly B(kt+2) in flight; barrier; prio1; 16 MFMA; prio0;
//        barrier
// Ledger: prologue 8 loads -> vmcnt(2) (A0,B0 landed; B1 in flight). Steady:
// 2 outstanding at iter entry, +4 (PH0) +2 (PH1) = 8, wait 2 drains
// B(kt+1)+A(kt+1). Tail clamps re-stage identical data (benign). vmcnt(0)
// after the K-loop so dangling prefetches can't corrupt the next item.
template <int K, int KS, int NB, bool SECOND>
__global__ __launch_bounds__(512, 2) void ffn_gemm8(
    const u16* __restrict__ A, const u16* __restrict__ B,
    const float* __restrict__ bias, u16* __restrict__ hdn_out,
    float* __restrict__ out, const int* __restrict__ row_token,
    const float* __restrict__ row_weight, const int* __restrict__ tile_e,
    const int* __restrict__ tile_m0, const int* __restrict__ tile_nrows,
    const int* __restrict__ num_tiles, int* __restrict__ work_ctr, int N) {
  constexpr int KT = K / KS / 64;      // K-tiles per item
  constexpr int PER_TILE = NB * KS;

  __shared__ u16 sA[2][2 * 128 * 64];
  __shared__ u16 sB[2][128 * 64];
  __shared__ int s_item;

  int tid = threadIdx.x;
  int lane = tid & 63;
  int wave = tid >> 6;             // 0..7
  int wm = wave >> 2, wn = wave & 3;
  int l15 = lane & 15, quad = lane >> 4;
  int r7 = l15 & 7;

  // staging geometry: half-tile 128x64 = 16KB = 512thr x 2 x 16B
  int c0 = tid, c1 = tid + 512;
  int r0s = c0 >> 3, j0 = ((c0 & 7) ^ (r0s & 7)) * 8;
  int r1s = c1 >> 3, j1 = ((c1 & 7) ^ (r1s & 7)) * 8;

  int jxk[2];
#pragma unroll
  for (int ks = 0; ks < 2; ++ks) jxk[ks] = ((ks * 4 + quad) ^ r7) * 8;

  int total = (*num_tiles) * PER_TILE;

  for (;;) {
    if (tid == 0) s_item = atomicAdd(work_ctr, 1);
    __syncthreads();
    int its = s_item;
    if (its >= total) break;

    int tile = its / PER_TILE;
    int rem = its - tile * PER_TILE;
    int nb = rem % NB;
    int ksp = rem / NB;

    int e = tile_e[tile];
    int row0 = tile_m0[tile];
    int nrows = tile_nrows[tile];
    int n0 = nb * 128;
    int korg = ksp * (K / KS);

    const u16* Ab = A + (size_t)row0 * K + korg;
    const u16* Bb = B + (size_t)e * (size_t)N * K + (size_t)n0 * K + korg;

    auto stageA = [&](int db, int sk, int ha) {
      async_copy16(Ab + (size_t)(ha * 128 + r0s) * K + sk * 64 + j0,
                   &sA[db][ha * 8192 + c0 * 8]);
      async_copy16(Ab + (size_t)(ha * 128 + r1s) * K + sk * 64 + j1,
                   &sA[db][ha * 8192 + c1 * 8]);
    };
    auto stageB = [&](int db, int sk) {
      async_copy16(Bb + (size_t)r0s * K + sk * 64 + j0, &sB[db][c0 * 8]);
      async_copy16(Bb + (size_t)r1s * K + sk * 64 + j1, &sB[db][c1 * 8]);
    };

    f32x4 acc[8][2];
#pragma unroll
    for (int am = 0; am < 8; ++am)
#pragma unroll
      for (int an = 0; an < 2; ++an) acc[am][an] = (f32x4){0.f, 0.f, 0.f, 0.f};

    // prologue: A(0) both halves, B(0), B(1)  -> 8 loads, keep B(1) in flight
    stageA(0, 0, 0); stageA(0, 0, 1);
    stageB(0, 0);
    stageB(1, 1);
    asm volatile("s_waitcnt vmcnt(2)" ::: "memory");
    __builtin_amdgcn_s_barrier();

    for (int kt = 0; kt < KT; ++kt) {
      int cb = kt & 1, pb = cb ^ 1;
      int ka = kt + 1 < KT ? kt + 1 : KT - 1;
      int kb = kt + 2 < KT ? kt + 2 : KT - 1;
      const u16* sAc = sA[cb];
      const u16* sBc = sB[cb];

      bf16x8 bfr[2][2];
#pragma unroll
      for (int ks = 0; ks < 2; ++ks)
#pragma unroll
        for (int an = 0; an < 2; ++an)
          bfr[an][ks] = *(const bf16x8*)(sBc + ((wn * 2 + an) * 16 + l15) * 64 + jxk[ks]);

      // ---- PH0: acc rows 0..3 ----
      {
        bf16x8 af[4][2];
#pragma unroll
        for (int ks = 0; ks < 2; ++ks)
#pragma unroll
          for (int i = 0; i < 4; ++i)
            af[i][ks] = *(const bf16x8*)(sAc + (wm * 128 + i * 16 + l15) * 64 + jxk[ks]);
        stageA(pb, ka, 0);
        stageA(pb, ka, 1);
        __builtin_amdgcn_s_barrier();
        __builtin_amdgcn_s_setprio(1);
#pragma unroll
        for (int i = 0; i < 4; ++i)
#pragma unroll
          for (int an = 0; an < 2; ++an)
#pragma unroll
            for (int ks = 0; ks < 2; ++ks)
              acc[i][an] = __builtin_amdgcn_mfma_f32_16x16x32_bf16(af[i][ks], bfr[an][ks],
                                                                  acc[i][an], 0, 0, 0);
        __builtin_amdgcn_s_setprio(0);
        __builtin_amdgcn_s_barrier();
      }
      // ---- PH1: acc rows 4..7 ----
      {
        bf16x8 af[4][2];
#pragma unroll
        for (int ks = 0; ks < 2; ++ks)
#pragma unroll
          for (int i = 0; i < 4; ++i)
            af[i][ks] = *(const bf16x8*)(sAc + (wm * 128 + (4 + i) * 16 + l15) * 64 + jxk[ks]);
        stageB(cb, kb);
        asm volatile("s_waitcnt vmcnt(2)" ::: "memory");
        __builtin_amdgcn_s_barrier();
        __builtin_amdgcn_s_setprio(1);
#pragma unroll
        for (int i = 0; i < 4; ++i)
#pragma unroll
          for (int an = 0; an < 2; ++an)
#pragma unroll
            for (int ks = 0; ks < 2; ++ks)
              acc[4 + i][an] = __builtin_amdgcn_mfma_f32_16x16x32_bf16(af[i][ks], bfr[an][ks],
                                                                      acc[4 + i][an], 0, 0, 0);
        __builtin_amdgcn_s_setprio(0);
        __builtin_amdgcn_s_barrier();
      }
    }
    // drain dangling prefetches before the next item reuses the LDS buffers
    asm volatile("s_waitcnt vmcnt(0)" ::: "memory");

    if constexpr (!SECOND) {
#pragma unroll
      for (int an = 0; an < 2; ++an) {
        int col = n0 + (wn * 2 + an) * 16 + l15;
        float bv = bias[e * N + col];
#pragma unroll
        for (int am = 0; am < 8; ++am) {
#pragma unroll
          for (int r = 0; r < 4; ++r) {
            int lr = wm * 128 + am * 16 + quad * 4 + r;  // C/D: col=lane&15, row=quad*4+reg
            if (lr < nrows) {
              float vv = acc[am][an][r] + bv;
              vv = vv / (1.f + __expf(-vv));             // silu
              hdn_out[(size_t)(row0 + lr) * N + col] = f2bf(vv);
            }
          }
        }
      }
    } else {
      float bv[2];
#pragma unroll
      for (int an = 0; an < 2; ++an)
        bv[an] = (ksp == 0) ? bias[e * N + n0 + (wn * 2 + an) * 16 + l15] : 0.f;
#pragma unroll
      for (int am = 0; am < 8; ++am) {
#pragma unroll
        for (int r = 0; r < 4; ++r) {
          int lr = wm * 128 + am * 16 + quad * 4 + r;
          if (lr < nrows) {
            int grow = row0 + lr;
            int tok = row_token[grow];
            float w = row_weight[grow];
            float* orow = out + (size_t)tok * N;
#pragma unroll
            for (int an = 0; an < 2; ++an) {
              int col = n0 + (wn * 2 + an) * 16 + l15;
              atomicAdd(orow + col, (acc[am][an][r] + bv[an]) * w);
            }
          }
        }
      }
    }
  }
}

extern "C" void kernel_launch(void* const* d_in, const int* in_sizes, int n_in,
                              void* d_out, int out_size, void* d_ws, size_t ws_size,
                              hipStream_t stream) {
  const float* x  = (const float*)d_in[0];
  const float* Wg = (const float*)d_in[1];
  const float* W1 = (const float*)d_in[2];
  const float* b1 = (const float*)d_in[3];
  const float* W2 = (const float*)d_in[4];
  const float* b2 = (const float*)d_in[5];
  float* out = (float*)d_out;

  char* ws = (char*)d_ws;
  size_t off = 0;
  auto alloc = [&](size_t bytes) {
    void* p = ws + off;
    off += (bytes + 255) & ~(size_t)255;
    return p;
  };
  u16* W1T = (u16*)alloc((size_t)EXP * IDIM * HDIM * 2);   // 67 MB  [E][I][H]
  u16* W2T = (u16*)alloc((size_t)EXP * IDIM * HDIM * 2);   // 67 MB  [E][H][I]
  u16* xg  = (u16*)alloc((size_t)PAD_ROWS * HDIM * 2);     // 17 MB
  u16* hdn = (u16*)alloc((size_t)PAD_ROWS * IDIM * 2);     // 69 MB
  int*   sel_e      = (int*)alloc(NROWS * 4);
  float* sel_w      = (float*)alloc(NROWS * 4);
  int*   row_token  = (int*)alloc(NROWS * 4);
  float* row_weight = (float*)alloc(NROWS * 4);
  int* tile_e     = (int*)alloc(MAX_TILES * 4);
  int* tile_m0    = (int*)alloc(MAX_TILES * 4);
  int* tile_nrows = (int*)alloc(MAX_TILES * 4);
  int* num_tiles  = (int*)alloc(4);
  int* work_ctr   = (int*)alloc(2 * 4);

  hipMemsetAsync(d_out, 0, (size_t)out_size * sizeof(float), stream);
  transpose_convert<<<dim3(IDIM / 64, HDIM / 64, EXP), 256, 0, stream>>>(W1, W1T, HDIM, IDIM);
  transpose_convert<<<dim3(HDIM / 64, IDIM / 64, EXP), 256, 0, stream>>>(W2, W2T, IDIM, HDIM);
  gate_kernel<<<T_TOK / 4, 256, 0, stream>>>(x, Wg, sel_e, sel_w);
  route_kernel<<<1, 256, 0, stream>>>(sel_e, sel_w, row_token, row_weight,
                                      tile_e, tile_m0, tile_nrows, num_tiles, work_ctr);
  gather_kernel<<<NROWS, 256, 0, stream>>>(x, row_token, xg);
  // GEMM1: hdn = silu(xg @ W1 + b1); items = nt * (4096/128) = ~1088
  ffn_gemm8<HDIM, 1, 32, false><<<256, 512, 0, stream>>>(
      xg, W1T, b1, hdn, nullptr, nullptr, nullptr,
      tile_e, tile_m0, tile_nrows, num_tiles, work_ctr + 0, IDIM);
  // GEMM2: out += w * (hdn @ W2 + b2); split-K=2; items = nt * 8 * 2 = ~544
  ffn_gemm8<IDIM, 2, 8, true><<<256, 512, 0, stream>>>(
      hdn, W2T, b2, nullptr, out, row_token, row_weight,
      tile_e, tile_m0, tile_nrows, num_tiles, work_ctr + 1, HDIM);
}